// Round 2
// baseline (15371.220 us; speedup 1.0000x reference)
//
#include <hip/hip_runtime.h>
#include <cmath>

// Problem constants
#define Bb   32
#define Tt   512
#define INd  128
#define RES  2048
#define OUTd 64
#define NWIN 128            // (512 + 2*2 - 8)/4 + 1
#define NROW (Bb*NWIN)      // 4096

// GEMM tiling
#define BM 64
#define BN 64
#define BK 16

#define MICRO(SA, SB)                                                           \
  do {                                                                          \
    _Pragma("unroll")                                                           \
    for (int kk = 0; kk < BK; ++kk) {                                           \
      const float4 a4 = *(const float4*)&SA[kk][ty << 2];                       \
      const float4 b4 = *(const float4*)&SB[kk][tx << 2];                       \
      acc[0][0] += a4.x*b4.x; acc[0][1] += a4.x*b4.y;                           \
      acc[0][2] += a4.x*b4.z; acc[0][3] += a4.x*b4.w;                           \
      acc[1][0] += a4.y*b4.x; acc[1][1] += a4.y*b4.y;                           \
      acc[1][2] += a4.y*b4.z; acc[1][3] += a4.y*b4.w;                           \
      acc[2][0] += a4.z*b4.x; acc[2][1] += a4.z*b4.y;                           \
      acc[2][2] += a4.z*b4.z; acc[2][3] += a4.z*b4.w;                           \
      acc[3][0] += a4.w*b4.x; acc[3][1] += a4.w*b4.y;                           \
      acc[3][2] += a4.w*b4.z; acc[3][3] += a4.w*b4.w;                           \
    }                                                                           \
  } while (0)

// One reservoir step: Sout = 0.7*Sin + 0.3*sin(Sin@Wres + x_s@Win)
// State storage:
//   s=0: write S0 (linear rows r=b*128+w), no Sin
//   s=1: read S0 linear, write S1 linear
//   s=2: read S1 linear, write RS rows b*512+4w+0
//   s>=3: read RS rows b*512+4w+(s-3), write RS rows b*512+4w+(s-2)
__global__ __launch_bounds__(256)
void step_kernel(const float* Sin, const float* __restrict__ X,
                 const float* __restrict__ Wres, const float* __restrict__ Win,
                 float* Out, int s)
{
    __shared__ float St[BK][BM + 4];
    __shared__ float Wt[BK][BN + 4];
    const int tid  = threadIdx.x;
    const int row0 = blockIdx.y * BM;     // logical state-row tile (r = b*128+w)
    const int q0   = blockIdx.x * BN;     // N tile (reservoir cols)
    const int b    = row0 / NWIN;         // BM=64 divides NWIN=128 -> uniform b
    const int w0   = row0 % NWIN;

    const int li = tid >> 2;              // 0..63 : tile row for A-load
    const int lk = (tid & 3) << 2;        // 0,4,8,12 : k offset (float4)
    const int wk = tid >> 4;              // 0..15 : k row for B-load
    const int wq = (tid & 15) << 2;       // 0..60 : col offset (float4)
    const int ty = tid >> 4;              // micro-tile coords
    const int tx = tid & 15;

    float acc[4][4] = {};

    if (s > 0) {
        const int srowi = (s <= 2) ? (row0 + li)
                                   : (b * Tt + 4 * (w0 + li) + (s - 3));
        const float* srow = Sin + (size_t)srowi * RES + lk;
        for (int k0 = 0; k0 < RES; k0 += BK) {
            const float4 sv = *(const float4*)(srow + k0);
            St[lk + 0][li] = sv.x; St[lk + 1][li] = sv.y;
            St[lk + 2][li] = sv.z; St[lk + 3][li] = sv.w;
            *(float4*)&Wt[wk][wq] =
                *(const float4*)(Wres + (size_t)(k0 + wk) * RES + q0 + wq);
            __syncthreads();
            MICRO(St, Wt);
            __syncthreads();
        }
    }
    {   // input projection part: K = 128 over x[b, 4*w+s-2, :] @ Win
        const int t = 4 * (w0 + li) + s - 2;           // t <= 511 always
        const float* xrow = (t >= 0) ? (X + ((size_t)b * Tt + t) * INd + lk)
                                     : nullptr;
        for (int k0 = 0; k0 < INd; k0 += BK) {
            float4 sv = make_float4(0.f, 0.f, 0.f, 0.f);
            if (xrow) sv = *(const float4*)(xrow + k0);
            St[lk + 0][li] = sv.x; St[lk + 1][li] = sv.y;
            St[lk + 2][li] = sv.z; St[lk + 3][li] = sv.w;
            *(float4*)&Wt[wk][wq] =
                *(const float4*)(Win + (size_t)(k0 + wk) * RES + q0 + wq);
            __syncthreads();
            MICRO(St, Wt);
            __syncthreads();
        }
    }
    // epilogue
    const int coff = q0 + (tx << 2);
#pragma unroll
    for (int a = 0; a < 4; ++a) {
        const int row = row0 + (ty << 2) + a;          // logical state row
        const int w   = row % NWIN;
        float4 prev = make_float4(0.f, 0.f, 0.f, 0.f);
        if (s > 0) {
            const int sidx = (s <= 2) ? row : (b * Tt + 4 * w + (s - 3));
            prev = *(const float4*)(Sin + (size_t)sidx * RES + coff);
        }
        float4 o4;
        o4.x = 0.7f * prev.x + 0.3f * sinf(acc[a][0]);
        o4.y = 0.7f * prev.y + 0.3f * sinf(acc[a][1]);
        o4.z = 0.7f * prev.z + 0.3f * sinf(acc[a][2]);
        o4.w = 0.7f * prev.w + 0.3f * sinf(acc[a][3]);
        const int oidx = (s < 2) ? row : (b * Tt + 4 * w + (s - 2));
        *(float4*)(Out + (size_t)oidx * RES + coff) = o4;
    }
}

// A[b] = Xb@Xb^T + softplus(lam)*I ; Xb = [RS_b (512x2048) | ones]
// Symmetric: only tile pairs ti<=tj launched (36 of 64), write both halves.
__global__ __launch_bounds__(256)
void gram_kernel(const float* __restrict__ RS, float* __restrict__ A,
                 const float* __restrict__ lam)
{
    __shared__ float Ut[BK][BM + 4];
    __shared__ float Vt[BK][BN + 4];
    const int tid = threadIdx.x;
    const int bt  = blockIdx.y;
    int ti = 0, rem = (int)blockIdx.x;
    while (rem >= 8 - ti) { rem -= 8 - ti; ++ti; }
    const int tj = ti + rem;
    const int n0 = ti * 64, m0 = tj * 64;
    const float* base = RS + (size_t)bt * Tt * RES;

    const int li = tid >> 2, lk = (tid & 3) << 2;
    const int ty = tid >> 4, tx = tid & 15;
    float acc[4][4] = {};

    for (int k0 = 0; k0 < RES; k0 += BK) {
        const float4 u = *(const float4*)(base + (size_t)(n0 + li) * RES + k0 + lk);
        const float4 v = *(const float4*)(base + (size_t)(m0 + li) * RES + k0 + lk);
        Ut[lk + 0][li] = u.x; Ut[lk + 1][li] = u.y;
        Ut[lk + 2][li] = u.z; Ut[lk + 3][li] = u.w;
        Vt[lk + 0][li] = v.x; Vt[lk + 1][li] = v.y;
        Vt[lk + 2][li] = v.z; Vt[lk + 3][li] = v.w;
        __syncthreads();
        MICRO(Ut, Vt);
        __syncthreads();
    }
    const float reg = log1pf(expf(lam[0]));   // softplus(0) = ln 2
    float* Ab = A + (size_t)bt * 512 * 512;
#pragma unroll
    for (int a = 0; a < 4; ++a) {
        const int nn = n0 + (ty << 2) + a;
#pragma unroll
        for (int c = 0; c < 4; ++c) {
            const int mm = m0 + (tx << 2) + c;
            float val = acc[a][c] + 1.0f;     // ones-column contribution
            if (nn == mm) val += reg;
            Ab[(size_t)nn * 512 + mm] = val;
            Ab[(size_t)mm * 512 + nn] = val;
        }
    }
}

// In-place lower Cholesky of A[b] (512x512) then solve L L^T Z = Y[b].
// One 512-thread block per batch; A is ~1MB -> per-XCD-L2 resident.
__global__ __launch_bounds__(512)
void chol_solve_kernel(float* __restrict__ Aall, const float* __restrict__ Y,
                       float* __restrict__ Zall)
{
    const int n = 512;
    const int b = blockIdx.x, tid = threadIdx.x;
    float* A        = Aall + (size_t)b * n * n;
    const float* Yb = Y    + (size_t)b * n * OUTd;
    float* Z        = Zall + (size_t)b * n * OUTd;
    __shared__ float col[512];
    __shared__ float dsh;
    __shared__ float partial[8][64];

    // right-looking Cholesky, lower triangle only
    for (int j = 0; j < n; ++j) {
        if (tid == 0) dsh = sqrtf(A[(size_t)j * n + j]);
        __syncthreads();
        const float d = dsh;
        for (int i = j + 1 + tid; i < n; i += 512) {
            const float v = A[(size_t)i * n + j] / d;
            A[(size_t)i * n + j] = v;
            col[i] = v;
        }
        if (tid == 0) A[(size_t)j * n + j] = d;
        __syncthreads();
        const int lane = tid & 63, wv = tid >> 6;   // 8 waves
        for (int i = j + 1 + wv; i < n; i += 8) {
            const float ci = col[i];
            for (int k = j + 1 + lane; k <= i; k += 64)
                A[(size_t)i * n + k] -= ci * col[k];
        }
        __syncthreads();
    }
    // forward solve L V = Y  (V stored in Z)
    const int o = tid & 63, c = tid >> 6;
    for (int i = 0; i < n; ++i) {
        float p = 0.f;
        for (int k = c; k < i; k += 8)
            p += A[(size_t)i * n + k] * Z[(size_t)k * OUTd + o];
        partial[c][o] = p;
        __syncthreads();
        if (c == 0) {
            float s2 = 0.f;
#pragma unroll
            for (int q = 0; q < 8; ++q) s2 += partial[q][o];
            Z[(size_t)i * OUTd + o] =
                (Yb[(size_t)i * OUTd + o] - s2) / A[(size_t)i * n + i];
        }
        __syncthreads();
    }
    // back solve L^T Z = V (in place)
    for (int i = n - 1; i >= 0; --i) {
        float p = 0.f;
        for (int k = i + 1 + c; k < n; k += 8)
            p += A[(size_t)k * n + i] * Z[(size_t)k * OUTd + o];
        partial[c][o] = p;
        __syncthreads();
        if (c == 0) {
            float s2 = 0.f;
#pragma unroll
            for (int q = 0; q < 8; ++q) s2 += partial[q][o];
            Z[(size_t)i * OUTd + o] =
                (Z[(size_t)i * OUTd + o] - s2) / A[(size_t)i * n + i];
        }
        __syncthreads();
    }
}

// w[b] (2048x64) = RS_b^T @ Z_b   (K = 512)
__global__ __launch_bounds__(256)
void out_kernel(const float* __restrict__ RS, const float* __restrict__ Z,
                float* __restrict__ Wout)
{
    __shared__ float Rt[BK][64 + 4];
    __shared__ float Zt[BK][64 + 4];
    const int tid = threadIdx.x;
    const int b   = blockIdx.y;
    const int d0  = blockIdx.x * 64;
    const int kk  = tid >> 4, cq = (tid & 15) << 2;
    const int ty  = tid >> 4, tx = tid & 15;
    float acc[4][4] = {};

    for (int k0 = 0; k0 < Tt; k0 += BK) {
        *(float4*)&Rt[kk][cq] =
            *(const float4*)(RS + ((size_t)b * Tt + k0 + kk) * RES + d0 + cq);
        *(float4*)&Zt[kk][cq] =
            *(const float4*)(Z + ((size_t)b * Tt + k0 + kk) * OUTd + cq);
        __syncthreads();
        MICRO(Rt, Zt);
        __syncthreads();
    }
#pragma unroll
    for (int a = 0; a < 4; ++a) {
        const int d = d0 + (ty << 2) + a;
        float4 v = make_float4(acc[a][0], acc[a][1], acc[a][2], acc[a][3]);
        *(float4*)(Wout + ((size_t)b * RES + d) * OUTd + (tx << 2)) = v;
    }
}

// bias[b][o] = sum_n Z[b][n][o]  (ones-row of Xb^T @ Z)
__global__ __launch_bounds__(64)
void bias_kernel(const float* __restrict__ Z, float* __restrict__ Bout)
{
    const int b = blockIdx.x, o = threadIdx.x;
    const float* Zb = Z + (size_t)b * Tt * OUTd;
    float s = 0.f;
    for (int n = 0; n < Tt; ++n) s += Zb[(size_t)n * OUTd + o];
    Bout[(size_t)b * OUTd + o] = s;
}

extern "C" void kernel_launch(void* const* d_in, const int* in_sizes, int n_in,
                              void* d_out, int out_size, void* d_ws, size_t ws_size,
                              hipStream_t stream)
{
    const float* X    = (const float*)d_in[0];   // (32,512,128)
    const float* Y    = (const float*)d_in[1];   // (32,512,64)
    const float* Wres = (const float*)d_in[2];   // (2048,2048)
    const float* Win  = (const float*)d_in[3];   // (128,2048)
    const float* lam  = (const float*)d_in[4];   // scalar

    float* out  = (float*)d_out;
    float* Wout = out;                            // 32*2048*64
    float* Bout = out + (size_t)Bb * RES * OUTd;  // 32*64

    // workspace layout (floats): S0 | S1 | RS = 8M | 8M | 32M floats = 192 MB.
    // A (8M floats) overlays S0, Z (1M floats) overlays S1 — both only live
    // after the step sequence no longer needs S0/S1.
    float* ws  = (float*)d_ws;
    float* S0  = ws;
    float* S1  = S0 + (size_t)NROW * RES;
    float* RSb = S1 + (size_t)NROW * RES;
    float* A   = S0;
    float* Z   = S1;

    const dim3 sgrid(RES / BN, NROW / BM);   // (32, 64)
    const dim3 blk(256);
    step_kernel<<<sgrid, blk, 0, stream>>>(nullptr, X, Wres, Win, S0, 0);
    step_kernel<<<sgrid, blk, 0, stream>>>(S0, X, Wres, Win, S1, 1);
    step_kernel<<<sgrid, blk, 0, stream>>>(S1, X, Wres, Win, RSb, 2);
    step_kernel<<<sgrid, blk, 0, stream>>>(RSb, X, Wres, Win, RSb, 3);
    step_kernel<<<sgrid, blk, 0, stream>>>(RSb, X, Wres, Win, RSb, 4);
    step_kernel<<<sgrid, blk, 0, stream>>>(RSb, X, Wres, Win, RSb, 5);

    gram_kernel<<<dim3(36, Bb), blk, 0, stream>>>(RSb, A, lam);
    chol_solve_kernel<<<dim3(Bb), dim3(512), 0, stream>>>(A, Y, Z);
    out_kernel<<<dim3(RES / 64, Bb), blk, 0, stream>>>(RSb, Z, Wout);
    bias_kernel<<<dim3(Bb), dim3(OUTd), 0, stream>>>(Z, Bout);
}

// Round 3
// 8014.893 us; speedup vs baseline: 1.9178x; 1.9178x over previous
//
#include <hip/hip_runtime.h>
#include <cmath>

// Problem constants
#define Bb   32
#define Tt   512
#define INd  128
#define RES  2048
#define OUTd 64
#define NWIN 128            // (512 + 2*2 - 8)/4 + 1
#define NROW (Bb*NWIN)      // 4096

// GEMM tiling
#define BM 64
#define BN 64
#define BK 16

#define MICRO(SA, SB)                                                           \
  do {                                                                          \
    _Pragma("unroll")                                                           \
    for (int kk = 0; kk < BK; ++kk) {                                           \
      const float4 a4 = *(const float4*)&SA[kk][ty << 2];                       \
      const float4 b4 = *(const float4*)&SB[kk][tx << 2];                       \
      acc[0][0] += a4.x*b4.x; acc[0][1] += a4.x*b4.y;                           \
      acc[0][2] += a4.x*b4.z; acc[0][3] += a4.x*b4.w;                           \
      acc[1][0] += a4.y*b4.x; acc[1][1] += a4.y*b4.y;                           \
      acc[1][2] += a4.y*b4.z; acc[1][3] += a4.y*b4.w;                           \
      acc[2][0] += a4.z*b4.x; acc[2][1] += a4.z*b4.y;                           \
      acc[2][2] += a4.z*b4.z; acc[2][3] += a4.z*b4.w;                           \
      acc[3][0] += a4.w*b4.x; acc[3][1] += a4.w*b4.y;                           \
      acc[3][2] += a4.w*b4.z; acc[3][3] += a4.w*b4.w;                           \
    }                                                                           \
  } while (0)

// One reservoir step: Sout = 0.7*Sin + 0.3*sin(Sin@Wres + x_s@Win)
__global__ __launch_bounds__(256)
void step_kernel(const float* Sin, const float* __restrict__ X,
                 const float* __restrict__ Wres, const float* __restrict__ Win,
                 float* Out, int s)
{
    __shared__ float St[BK][BM + 4];
    __shared__ float Wt[BK][BN + 4];
    const int tid  = threadIdx.x;
    const int row0 = blockIdx.y * BM;     // logical state-row tile (r = b*128+w)
    const int q0   = blockIdx.x * BN;     // N tile (reservoir cols)
    const int b    = row0 / NWIN;
    const int w0   = row0 % NWIN;

    const int li = tid >> 2;
    const int lk = (tid & 3) << 2;
    const int wk = tid >> 4;
    const int wq = (tid & 15) << 2;
    const int ty = tid >> 4;
    const int tx = tid & 15;

    float acc[4][4] = {};

    if (s > 0) {
        const int srowi = (s <= 2) ? (row0 + li)
                                   : (b * Tt + 4 * (w0 + li) + (s - 3));
        const float* srow = Sin + (size_t)srowi * RES + lk;
        for (int k0 = 0; k0 < RES; k0 += BK) {
            const float4 sv = *(const float4*)(srow + k0);
            St[lk + 0][li] = sv.x; St[lk + 1][li] = sv.y;
            St[lk + 2][li] = sv.z; St[lk + 3][li] = sv.w;
            *(float4*)&Wt[wk][wq] =
                *(const float4*)(Wres + (size_t)(k0 + wk) * RES + q0 + wq);
            __syncthreads();
            MICRO(St, Wt);
            __syncthreads();
        }
    }
    {   // input projection: K = 128 over x[b, 4*w+s-2, :] @ Win
        const int t = 4 * (w0 + li) + s - 2;
        const float* xrow = (t >= 0) ? (X + ((size_t)b * Tt + t) * INd + lk)
                                     : nullptr;
        for (int k0 = 0; k0 < INd; k0 += BK) {
            float4 sv = make_float4(0.f, 0.f, 0.f, 0.f);
            if (xrow) sv = *(const float4*)(xrow + k0);
            St[lk + 0][li] = sv.x; St[lk + 1][li] = sv.y;
            St[lk + 2][li] = sv.z; St[lk + 3][li] = sv.w;
            *(float4*)&Wt[wk][wq] =
                *(const float4*)(Win + (size_t)(k0 + wk) * RES + q0 + wq);
            __syncthreads();
            MICRO(St, Wt);
            __syncthreads();
        }
    }
    const int coff = q0 + (tx << 2);
#pragma unroll
    for (int a = 0; a < 4; ++a) {
        const int row = row0 + (ty << 2) + a;
        const int w   = row % NWIN;
        float4 prev = make_float4(0.f, 0.f, 0.f, 0.f);
        if (s > 0) {
            const int sidx = (s <= 2) ? row : (b * Tt + 4 * w + (s - 3));
            prev = *(const float4*)(Sin + (size_t)sidx * RES + coff);
        }
        float4 o4;
        o4.x = 0.7f * prev.x + 0.3f * sinf(acc[a][0]);
        o4.y = 0.7f * prev.y + 0.3f * sinf(acc[a][1]);
        o4.z = 0.7f * prev.z + 0.3f * sinf(acc[a][2]);
        o4.w = 0.7f * prev.w + 0.3f * sinf(acc[a][3]);
        const int oidx = (s < 2) ? row : (b * Tt + 4 * w + (s - 2));
        *(float4*)(Out + (size_t)oidx * RES + coff) = o4;
    }
}

// A[b] = Xb@Xb^T + softplus(lam)*I ; Xb = [RS_b (512x2048) | ones]
__global__ __launch_bounds__(256)
void gram_kernel(const float* __restrict__ RS, float* __restrict__ A,
                 const float* __restrict__ lam)
{
    __shared__ float Ut[BK][BM + 4];
    __shared__ float Vt[BK][BN + 4];
    const int tid = threadIdx.x;
    const int bt  = blockIdx.y;
    int ti = 0, rem = (int)blockIdx.x;
    while (rem >= 8 - ti) { rem -= 8 - ti; ++ti; }
    const int tj = ti + rem;
    const int n0 = ti * 64, m0 = tj * 64;
    const float* base = RS + (size_t)bt * Tt * RES;

    const int li = tid >> 2, lk = (tid & 3) << 2;
    const int ty = tid >> 4, tx = tid & 15;
    float acc[4][4] = {};

    for (int k0 = 0; k0 < RES; k0 += BK) {
        const float4 u = *(const float4*)(base + (size_t)(n0 + li) * RES + k0 + lk);
        const float4 v = *(const float4*)(base + (size_t)(m0 + li) * RES + k0 + lk);
        Ut[lk + 0][li] = u.x; Ut[lk + 1][li] = u.y;
        Ut[lk + 2][li] = u.z; Ut[lk + 3][li] = u.w;
        Vt[lk + 0][li] = v.x; Vt[lk + 1][li] = v.y;
        Vt[lk + 2][li] = v.z; Vt[lk + 3][li] = v.w;
        __syncthreads();
        MICRO(Ut, Vt);
        __syncthreads();
    }
    const float reg = log1pf(expf(lam[0]));   // softplus(0) = ln 2
    float* Ab = A + (size_t)bt * 512 * 512;
#pragma unroll
    for (int a = 0; a < 4; ++a) {
        const int nn = n0 + (ty << 2) + a;
#pragma unroll
        for (int c = 0; c < 4; ++c) {
            const int mm = m0 + (tx << 2) + c;
            float val = acc[a][c] + 1.0f;
            if (nn == mm) val += reg;
            Ab[(size_t)nn * 512 + mm] = val;
            Ab[(size_t)mm * 512 + nn] = val;
        }
    }
}

// ---- Blocked Cholesky ----
// Panel factor: factor A[64k:512, 64k:64k+64] (diag chol + TRSM below) in LDS.
// One block per batch. P stride 65 -> column accesses conflict-free.
__global__ __launch_bounds__(512)
void chol_panel_kernel(float* __restrict__ Aall, int k)
{
    __shared__ float P[512][65];
    __shared__ float dsh;
    float* A = Aall + (size_t)blockIdx.x * 512 * 512;
    const int tid  = threadIdx.x;
    const int j0   = 64 * k;
    const int rows = 512 - j0;
    const int c4   = (tid & 15) << 2;

    for (int r = tid >> 4; r < rows; r += 32) {
        const float4 v = *(const float4*)(A + (size_t)(j0 + r) * 512 + j0 + c4);
        P[r][c4 + 0] = v.x; P[r][c4 + 1] = v.y;
        P[r][c4 + 2] = v.z; P[r][c4 + 3] = v.w;
    }
    __syncthreads();

    const int lane = tid & 63, wv = tid >> 6;
    for (int j = 0; j < 64; ++j) {
        if (tid == 0) dsh = sqrtf(P[j][j]);
        __syncthreads();
        const float rd = 1.0f / dsh;
        for (int i = j + 1 + tid; i < rows; i += 512)
            P[i][j] *= rd;
        if (tid == 0) P[j][j] = dsh;
        __syncthreads();
        // rank-1: rows i>j, cols c in (j, 64), lower only (c<=i)
        const int c = j + 1 + lane;
        for (int i = j + 1 + wv; i < rows; i += 8) {
            const float lij = P[i][j];
            if (c < 64 && c <= i)
                P[i][c] -= lij * P[c][j];
        }
        __syncthreads();
    }

    for (int r = tid >> 4; r < rows; r += 32) {
        const float4 v = make_float4(P[r][c4], P[r][c4 + 1],
                                     P[r][c4 + 2], P[r][c4 + 3]);
        *(float4*)(A + (size_t)(j0 + r) * 512 + j0 + c4) = v;
    }
}

// Trailing update: A[64ti.., 64tj..] -= L[64ti.., panel k] @ L[64tj.., panel k]^T
// grid.x enumerates lower-triangle tile pairs (ti>=tj>k), grid.y = batch.
__global__ __launch_bounds__(256)
void chol_trailing_kernel(float* __restrict__ Aall, int k)
{
    __shared__ float Ut[BK][BM + 4];
    __shared__ float Vt[BK][BN + 4];
    float* A = Aall + (size_t)blockIdx.y * 512 * 512;
    const int tid = threadIdx.x;
    int a = 0, rem = (int)blockIdx.x;
    while (rem >= a + 1) { rem -= a + 1; ++a; }
    const int ti = k + 1 + a, tj = k + 1 + rem;
    const int i0 = ti * 64, j0c = tj * 64, p0 = k * 64;

    const int li = tid >> 2, lk = (tid & 3) << 2;
    const int ty = tid >> 4, tx = tid & 15;
    float acc[4][4] = {};

    for (int k0 = 0; k0 < 64; k0 += BK) {
        const float4 u = *(const float4*)(A + (size_t)(i0 + li) * 512 + p0 + k0 + lk);
        const float4 v = *(const float4*)(A + (size_t)(j0c + li) * 512 + p0 + k0 + lk);
        Ut[lk + 0][li] = u.x; Ut[lk + 1][li] = u.y;
        Ut[lk + 2][li] = u.z; Ut[lk + 3][li] = u.w;
        Vt[lk + 0][li] = v.x; Vt[lk + 1][li] = v.y;
        Vt[lk + 2][li] = v.z; Vt[lk + 3][li] = v.w;
        __syncthreads();
        MICRO(Ut, Vt);
        __syncthreads();
    }
#pragma unroll
    for (int aa = 0; aa < 4; ++aa) {
        const int r = i0 + (ty << 2) + aa;
        float* crow = A + (size_t)r * 512 + j0c + (tx << 2);
        float4 cv = *(const float4*)crow;
        cv.x -= acc[aa][0]; cv.y -= acc[aa][1];
        cv.z -= acc[aa][2]; cv.w -= acc[aa][3];
        *(float4*)crow = cv;
    }
}

// Blocked forward+backward triangular solve, Z (512x64) LDS-resident.
__global__ __launch_bounds__(512)
void fb_solve_kernel(const float* __restrict__ Aall, const float* __restrict__ Y,
                     float* __restrict__ Zall)
{
    __shared__ float Zsh[512][64];
    __shared__ float Lt[64][65];
    __shared__ float rdiag[64];
    const int b = blockIdx.x, tid = threadIdx.x;
    const float* A  = Aall + (size_t)b * 512 * 512;
    const float* Yb = Y    + (size_t)b * 512 * OUTd;
    float* Z        = Zall + (size_t)b * 512 * OUTd;
    const int o = tid & 63, wv = tid >> 6;

    for (int t = tid; t < 512 * 16; t += 512) {
        const int row = t >> 4, col4 = (t & 15) << 2;
        *(float4*)&Zsh[row][col4] = *(const float4*)(Yb + (size_t)row * 64 + col4);
    }
    __syncthreads();

    // forward: L V = Y
    for (int kb = 0; kb < 8; ++kb) {
        const int r0 = kb * 64;
        if (kb > 0) {
            for (int r = wv; r < 64; r += 8) {
                const float* Arow = A + (size_t)(r0 + r) * 512;
                float s2 = 0.f;
                for (int m2 = 0; m2 < r0; ++m2)
                    s2 += Arow[m2] * Zsh[m2][o];
                Zsh[r0 + r][o] -= s2;
            }
        }
        __syncthreads();
        for (int t = tid; t < 64 * 64; t += 512) {
            const int r = t >> 6, c = t & 63;
            Lt[r][c] = A[(size_t)(r0 + r) * 512 + r0 + c];
        }
        __syncthreads();
        if (tid < 64) rdiag[tid] = 1.0f / Lt[tid][tid];
        __syncthreads();
        for (int j = 0; j < 64; ++j) {          // deferred scaling: 1 barrier/row
            const float x = Zsh[r0 + j][o] * rdiag[j];
            for (int r = j + 1 + wv; r < 64; r += 8)
                Zsh[r0 + r][o] -= Lt[r][j] * x;
            __syncthreads();
        }
        for (int r = wv; r < 64; r += 8)
            Zsh[r0 + r][o] *= rdiag[r];
        __syncthreads();
    }

    // backward: L^T Z = V
    for (int kb = 7; kb >= 0; --kb) {
        const int r0 = kb * 64;
        if (kb < 7) {
            for (int r = wv; r < 64; r += 8) {
                const float* Acol = A + r0 + r;
                float s2 = 0.f;
                for (int m2 = r0 + 64; m2 < 512; ++m2)
                    s2 += Acol[(size_t)m2 * 512] * Zsh[m2][o];
                Zsh[r0 + r][o] -= s2;
            }
        }
        __syncthreads();
        for (int t = tid; t < 64 * 64; t += 512) {
            const int r = t >> 6, c = t & 63;
            Lt[r][c] = A[(size_t)(r0 + r) * 512 + r0 + c];
        }
        __syncthreads();
        if (tid < 64) rdiag[tid] = 1.0f / Lt[tid][tid];
        __syncthreads();
        for (int j = 63; j >= 0; --j) {
            const float x = Zsh[r0 + j][o] * rdiag[j];
            for (int r = wv; r < j; r += 8)
                Zsh[r0 + r][o] -= Lt[j][r] * x;
            __syncthreads();
        }
        for (int r = wv; r < 64; r += 8)
            Zsh[r0 + r][o] *= rdiag[r];
        __syncthreads();
    }

    for (int t = tid; t < 512 * 16; t += 512) {
        const int row = t >> 4, col4 = (t & 15) << 2;
        *(float4*)(Z + (size_t)row * 64 + col4) = *(const float4*)&Zsh[row][col4];
    }
}

// w[b] (2048x64) = RS_b^T @ Z_b   (K = 512)
__global__ __launch_bounds__(256)
void out_kernel(const float* __restrict__ RS, const float* __restrict__ Z,
                float* __restrict__ Wout)
{
    __shared__ float Rt[BK][64 + 4];
    __shared__ float Zt[BK][64 + 4];
    const int tid = threadIdx.x;
    const int b   = blockIdx.y;
    const int d0  = blockIdx.x * 64;
    const int kk  = tid >> 4, cq = (tid & 15) << 2;
    const int ty  = tid >> 4, tx = tid & 15;
    float acc[4][4] = {};

    for (int k0 = 0; k0 < Tt; k0 += BK) {
        *(float4*)&Rt[kk][cq] =
            *(const float4*)(RS + ((size_t)b * Tt + k0 + kk) * RES + d0 + cq);
        *(float4*)&Zt[kk][cq] =
            *(const float4*)(Z + ((size_t)b * Tt + k0 + kk) * OUTd + cq);
        __syncthreads();
        MICRO(Rt, Zt);
        __syncthreads();
    }
#pragma unroll
    for (int a = 0; a < 4; ++a) {
        const int d = d0 + (ty << 2) + a;
        float4 v = make_float4(acc[a][0], acc[a][1], acc[a][2], acc[a][3]);
        *(float4*)(Wout + ((size_t)b * RES + d) * OUTd + (tx << 2)) = v;
    }
}

// bias[b][o] = sum_n Z[b][n][o]
__global__ __launch_bounds__(64)
void bias_kernel(const float* __restrict__ Z, float* __restrict__ Bout)
{
    const int b = blockIdx.x, o = threadIdx.x;
    const float* Zb = Z + (size_t)b * Tt * OUTd;
    float s = 0.f;
    for (int n = 0; n < Tt; ++n) s += Zb[(size_t)n * OUTd + o];
    Bout[(size_t)b * OUTd + o] = s;
}

extern "C" void kernel_launch(void* const* d_in, const int* in_sizes, int n_in,
                              void* d_out, int out_size, void* d_ws, size_t ws_size,
                              hipStream_t stream)
{
    const float* X    = (const float*)d_in[0];   // (32,512,128)
    const float* Y    = (const float*)d_in[1];   // (32,512,64)
    const float* Wres = (const float*)d_in[2];   // (2048,2048)
    const float* Win  = (const float*)d_in[3];   // (128,2048)
    const float* lam  = (const float*)d_in[4];   // scalar

    float* out  = (float*)d_out;
    float* Wout = out;                            // 32*2048*64
    float* Bout = out + (size_t)Bb * RES * OUTd;  // 32*64

    // workspace (floats): S0 | S1 | RS = 8M | 8M | 32M = 192 MB.
    // A overlays S0, Z overlays S1 (live only after steps finish).
    float* ws  = (float*)d_ws;
    float* S0  = ws;
    float* S1  = S0 + (size_t)NROW * RES;
    float* RSb = S1 + (size_t)NROW * RES;
    float* A   = S0;
    float* Z   = S1;

    const dim3 sgrid(RES / BN, NROW / BM);   // (32, 64)
    const dim3 blk(256);
    step_kernel<<<sgrid, blk, 0, stream>>>(nullptr, X, Wres, Win, S0, 0);
    step_kernel<<<sgrid, blk, 0, stream>>>(S0, X, Wres, Win, S1, 1);
    step_kernel<<<sgrid, blk, 0, stream>>>(S1, X, Wres, Win, RSb, 2);
    step_kernel<<<sgrid, blk, 0, stream>>>(RSb, X, Wres, Win, RSb, 3);
    step_kernel<<<sgrid, blk, 0, stream>>>(RSb, X, Wres, Win, RSb, 4);
    step_kernel<<<sgrid, blk, 0, stream>>>(RSb, X, Wres, Win, RSb, 5);

    gram_kernel<<<dim3(36, Bb), blk, 0, stream>>>(RSb, A, lam);

    for (int k = 0; k < 8; ++k) {
        chol_panel_kernel<<<dim3(Bb), dim3(512), 0, stream>>>(A, k);
        const int m = 7 - k;
        if (m > 0) {
            const int tiles = m * (m + 1) / 2;
            chol_trailing_kernel<<<dim3(tiles, Bb), blk, 0, stream>>>(A, k);
        }
    }
    fb_solve_kernel<<<dim3(Bb), dim3(512), 0, stream>>>(A, Y, Z);

    out_kernel<<<dim3(RES / 64, Bb), blk, 0, stream>>>(RSb, Z, Wout);
    bias_kernel<<<dim3(Bb), dim3(OUTd), 0, stream>>>(Z, Bout);
}

// Round 4
// 5564.618 us; speedup vs baseline: 2.7623x; 1.4403x over previous
//
#include <hip/hip_runtime.h>
#include <cmath>

// Problem constants
#define Bb   32
#define Tt   512
#define INd  128
#define RES  2048
#define OUTd 64
#define NWIN 128            // (512 + 2*2 - 8)/4 + 1
#define NROW (Bb*NWIN)      // 4096

// GEMM tiling
#define BM 64
#define BN 64
#define BK 16

#define MICRO(SA, SB)                                                           \
  do {                                                                          \
    _Pragma("unroll")                                                           \
    for (int kk = 0; kk < BK; ++kk) {                                           \
      const float4 a4 = *(const float4*)&SA[kk][ty << 2];                       \
      const float4 b4 = *(const float4*)&SB[kk][tx << 2];                       \
      acc[0][0] += a4.x*b4.x; acc[0][1] += a4.x*b4.y;                           \
      acc[0][2] += a4.x*b4.z; acc[0][3] += a4.x*b4.w;                           \
      acc[1][0] += a4.y*b4.x; acc[1][1] += a4.y*b4.y;                           \
      acc[1][2] += a4.y*b4.z; acc[1][3] += a4.y*b4.w;                           \
      acc[2][0] += a4.z*b4.x; acc[2][1] += a4.z*b4.y;                           \
      acc[2][2] += a4.z*b4.z; acc[2][3] += a4.z*b4.w;                           \
      acc[3][0] += a4.w*b4.x; acc[3][1] += a4.w*b4.y;                           \
      acc[3][2] += a4.w*b4.z; acc[3][3] += a4.w*b4.w;                           \
    }                                                                           \
  } while (0)

// One reservoir step: Sout = 0.7*Sin + 0.3*sin(Sin@Wres + x_s@Win)
__global__ __launch_bounds__(256)
void step_kernel(const float* Sin, const float* __restrict__ X,
                 const float* __restrict__ Wres, const float* __restrict__ Win,
                 float* Out, int s)
{
    __shared__ float St[BK][BM + 4];
    __shared__ float Wt[BK][BN + 4];
    const int tid  = threadIdx.x;
    const int row0 = blockIdx.y * BM;
    const int q0   = blockIdx.x * BN;
    const int b    = row0 / NWIN;
    const int w0   = row0 % NWIN;

    const int li = tid >> 2;
    const int lk = (tid & 3) << 2;
    const int wk = tid >> 4;
    const int wq = (tid & 15) << 2;
    const int ty = tid >> 4;
    const int tx = tid & 15;

    float acc[4][4] = {};

    if (s > 0) {
        const int srowi = (s <= 2) ? (row0 + li)
                                   : (b * Tt + 4 * (w0 + li) + (s - 3));
        const float* srow = Sin + (size_t)srowi * RES + lk;
        for (int k0 = 0; k0 < RES; k0 += BK) {
            const float4 sv = *(const float4*)(srow + k0);
            St[lk + 0][li] = sv.x; St[lk + 1][li] = sv.y;
            St[lk + 2][li] = sv.z; St[lk + 3][li] = sv.w;
            *(float4*)&Wt[wk][wq] =
                *(const float4*)(Wres + (size_t)(k0 + wk) * RES + q0 + wq);
            __syncthreads();
            MICRO(St, Wt);
            __syncthreads();
        }
    }
    {   // input projection: K = 128 over x[b, 4*w+s-2, :] @ Win
        const int t = 4 * (w0 + li) + s - 2;
        const float* xrow = (t >= 0) ? (X + ((size_t)b * Tt + t) * INd + lk)
                                     : nullptr;
        for (int k0 = 0; k0 < INd; k0 += BK) {
            float4 sv = make_float4(0.f, 0.f, 0.f, 0.f);
            if (xrow) sv = *(const float4*)(xrow + k0);
            St[lk + 0][li] = sv.x; St[lk + 1][li] = sv.y;
            St[lk + 2][li] = sv.z; St[lk + 3][li] = sv.w;
            *(float4*)&Wt[wk][wq] =
                *(const float4*)(Win + (size_t)(k0 + wk) * RES + q0 + wq);
            __syncthreads();
            MICRO(St, Wt);
            __syncthreads();
        }
    }
    const int coff = q0 + (tx << 2);
#pragma unroll
    for (int a = 0; a < 4; ++a) {
        const int row = row0 + (ty << 2) + a;
        const int w   = row % NWIN;
        float4 prev = make_float4(0.f, 0.f, 0.f, 0.f);
        if (s > 0) {
            const int sidx = (s <= 2) ? row : (b * Tt + 4 * w + (s - 3));
            prev = *(const float4*)(Sin + (size_t)sidx * RES + coff);
        }
        float4 o4;
        o4.x = 0.7f * prev.x + 0.3f * sinf(acc[a][0]);
        o4.y = 0.7f * prev.y + 0.3f * sinf(acc[a][1]);
        o4.z = 0.7f * prev.z + 0.3f * sinf(acc[a][2]);
        o4.w = 0.7f * prev.w + 0.3f * sinf(acc[a][3]);
        const int oidx = (s < 2) ? row : (b * Tt + 4 * w + (s - 2));
        *(float4*)(Out + (size_t)oidx * RES + coff) = o4;
    }
}

// A[b] = Xb@Xb^T + softplus(lam)*I ; Xb = [RS_b (512x2048) | ones]
__global__ __launch_bounds__(256)
void gram_kernel(const float* __restrict__ RS, float* __restrict__ A,
                 const float* __restrict__ lam)
{
    __shared__ float Ut[BK][BM + 4];
    __shared__ float Vt[BK][BN + 4];
    const int tid = threadIdx.x;
    const int bt  = blockIdx.y;
    int ti = 0, rem = (int)blockIdx.x;
    while (rem >= 8 - ti) { rem -= 8 - ti; ++ti; }
    const int tj = ti + rem;
    const int n0 = ti * 64, m0 = tj * 64;
    const float* base = RS + (size_t)bt * Tt * RES;

    const int li = tid >> 2, lk = (tid & 3) << 2;
    const int ty = tid >> 4, tx = tid & 15;
    float acc[4][4] = {};

    for (int k0 = 0; k0 < RES; k0 += BK) {
        const float4 u = *(const float4*)(base + (size_t)(n0 + li) * RES + k0 + lk);
        const float4 v = *(const float4*)(base + (size_t)(m0 + li) * RES + k0 + lk);
        Ut[lk + 0][li] = u.x; Ut[lk + 1][li] = u.y;
        Ut[lk + 2][li] = u.z; Ut[lk + 3][li] = u.w;
        Vt[lk + 0][li] = v.x; Vt[lk + 1][li] = v.y;
        Vt[lk + 2][li] = v.z; Vt[lk + 3][li] = v.w;
        __syncthreads();
        MICRO(Ut, Vt);
        __syncthreads();
    }
    const float reg = log1pf(expf(lam[0]));   // softplus(0) = ln 2
    float* Ab = A + (size_t)bt * 512 * 512;
#pragma unroll
    for (int a = 0; a < 4; ++a) {
        const int nn = n0 + (ty << 2) + a;
#pragma unroll
        for (int c = 0; c < 4; ++c) {
            const int mm = m0 + (tx << 2) + c;
            float val = acc[a][c] + 1.0f;
            if (nn == mm) val += reg;
            Ab[(size_t)nn * 512 + mm] = val;
            Ab[(size_t)mm * 512 + nn] = val;
        }
    }
}

// ---- Blocked Cholesky ----
__global__ __launch_bounds__(512)
void chol_panel_kernel(float* __restrict__ Aall, int k)
{
    __shared__ float P[512][65];
    __shared__ float dsh;
    float* A = Aall + (size_t)blockIdx.x * 512 * 512;
    const int tid  = threadIdx.x;
    const int j0   = 64 * k;
    const int rows = 512 - j0;
    const int c4   = (tid & 15) << 2;

    for (int r = tid >> 4; r < rows; r += 32) {
        const float4 v = *(const float4*)(A + (size_t)(j0 + r) * 512 + j0 + c4);
        P[r][c4 + 0] = v.x; P[r][c4 + 1] = v.y;
        P[r][c4 + 2] = v.z; P[r][c4 + 3] = v.w;
    }
    __syncthreads();

    const int lane = tid & 63, wv = tid >> 6;
    for (int j = 0; j < 64; ++j) {
        if (tid == 0) dsh = sqrtf(P[j][j]);
        __syncthreads();
        const float rd = 1.0f / dsh;
        for (int i = j + 1 + tid; i < rows; i += 512)
            P[i][j] *= rd;
        if (tid == 0) P[j][j] = dsh;
        __syncthreads();
        const int c = j + 1 + lane;
        for (int i = j + 1 + wv; i < rows; i += 8) {
            const float lij = P[i][j];
            if (c < 64 && c <= i)
                P[i][c] -= lij * P[c][j];
        }
        __syncthreads();
    }

    for (int r = tid >> 4; r < rows; r += 32) {
        const float4 v = make_float4(P[r][c4], P[r][c4 + 1],
                                     P[r][c4 + 2], P[r][c4 + 3]);
        *(float4*)(A + (size_t)(j0 + r) * 512 + j0 + c4) = v;
    }
}

__global__ __launch_bounds__(256)
void chol_trailing_kernel(float* __restrict__ Aall, int k)
{
    __shared__ float Ut[BK][BM + 4];
    __shared__ float Vt[BK][BN + 4];
    float* A = Aall + (size_t)blockIdx.y * 512 * 512;
    const int tid = threadIdx.x;
    int a = 0, rem = (int)blockIdx.x;
    while (rem >= a + 1) { rem -= a + 1; ++a; }
    const int ti = k + 1 + a, tj = k + 1 + rem;
    const int i0 = ti * 64, j0c = tj * 64, p0 = k * 64;

    const int li = tid >> 2, lk = (tid & 3) << 2;
    const int ty = tid >> 4, tx = tid & 15;
    float acc[4][4] = {};

    for (int k0 = 0; k0 < 64; k0 += BK) {
        const float4 u = *(const float4*)(A + (size_t)(i0 + li) * 512 + p0 + k0 + lk);
        const float4 v = *(const float4*)(A + (size_t)(j0c + li) * 512 + p0 + k0 + lk);
        Ut[lk + 0][li] = u.x; Ut[lk + 1][li] = u.y;
        Ut[lk + 2][li] = u.z; Ut[lk + 3][li] = u.w;
        Vt[lk + 0][li] = v.x; Vt[lk + 1][li] = v.y;
        Vt[lk + 2][li] = v.z; Vt[lk + 3][li] = v.w;
        __syncthreads();
        MICRO(Ut, Vt);
        __syncthreads();
    }
#pragma unroll
    for (int aa = 0; aa < 4; ++aa) {
        const int r = i0 + (ty << 2) + aa;
        float* crow = A + (size_t)r * 512 + j0c + (tx << 2);
        float4 cv = *(const float4*)crow;
        cv.x -= acc[aa][0]; cv.y -= acc[aa][1];
        cv.z -= acc[aa][2]; cv.w -= acc[aa][3];
        *(float4*)crow = cv;
    }
}

// W_k = inv(L_kk) per (batch, diag block). One wave; W and W^T written out.
__global__ __launch_bounds__(64)
void tri_inv_kernel(const float* __restrict__ Aall, float* __restrict__ Winv,
                    float* __restrict__ WinvT)
{
    __shared__ float L[64][65];
    __shared__ float W[64][65];
    const int b = blockIdx.x >> 3, k = blockIdx.x & 7;
    const int c = threadIdx.x;
    const float* Ab = Aall + (size_t)b * 512 * 512;
    const int j0 = k * 64;

    for (int j = 0; j < 64; ++j) {
        L[j][c] = Ab[(size_t)(j0 + j) * 512 + j0 + c];
        W[j][c] = 0.f;
    }
    __syncthreads();
    for (int j = 0; j < 64; ++j) {
        float s = (j == c) ? 1.0f : 0.0f;
        for (int m = 0; m < j; ++m)
            s -= L[j][m] * W[m][c];
        W[j][c] = (c <= j) ? (s / L[j][j]) : 0.0f;
        __syncthreads();
    }
    float* Wo  = Winv  + ((size_t)b * 8 + k) * 64 * 64;
    float* WoT = WinvT + ((size_t)b * 8 + k) * 64 * 64;
    for (int j = 0; j < 64; ++j) {
        Wo[(size_t)j * 64 + c]  = W[j][c];
        WoT[(size_t)c * 64 + j] = W[j][c];
    }
}

// Blocked fwd+bwd solve via diag-block inverses; V (512x64) LDS-resident,
// all updates as LDS-tiled register GEMMs.
__global__ __launch_bounds__(256)
void fb_solve2_kernel(const float* __restrict__ Aall,
                      const float* __restrict__ Winv,
                      const float* __restrict__ WinvT,
                      const float* __restrict__ Y, float* __restrict__ Zall)
{
    __shared__ float V[512][64];      // 128 KB RHS, transformed in place
    __shared__ float St[BK][68];      // L tile (A-operand, [k][row])
    __shared__ float Wt[BK][68];      // W tile
    __shared__ float Ush[64][68];     // U scratch between the two GEMMs
    const int b   = blockIdx.x, tid = threadIdx.x;
    const float* A   = Aall + (size_t)b * 512 * 512;
    const float* Yb  = Y    + (size_t)b * 512 * OUTd;
    float* Z         = Zall + (size_t)b * 512 * OUTd;
    const float* Wb  = Winv  + (size_t)b * 8 * 64 * 64;
    const float* WbT = WinvT + (size_t)b * 8 * 64 * 64;

    const int li = tid >> 2, lk = (tid & 3) << 2;   // transpose-scatter stage
    const int wk = tid >> 4, wq = (tid & 15) << 2;  // direct-copy stage
    const int ty = tid >> 4, tx = tid & 15;

    for (int t = tid; t < 512 * 16; t += 256) {
        const int row = t >> 4, c4 = (t & 15) << 2;
        *(float4*)&V[row][c4] = *(const float4*)(Yb + (size_t)row * 64 + c4);
    }
    __syncthreads();

    // ---- forward: V_k = W_k (Y_k - L[k, 0:64k] @ V) ----
    for (int k = 0; k < 8; ++k) {
        const int r0 = k * 64;
        float acc[4][4] = {};
        for (int k0 = 0; k0 < r0; k0 += BK) {       // K over finalized rows
            const float4 u = *(const float4*)(A + (size_t)(r0 + li) * 512 + k0 + lk);
            St[lk + 0][li] = u.x; St[lk + 1][li] = u.y;
            St[lk + 2][li] = u.z; St[lk + 3][li] = u.w;
            __syncthreads();
            MICRO(St, (V + k0));
            __syncthreads();
        }
#pragma unroll
        for (int a = 0; a < 4; ++a)
#pragma unroll
            for (int c = 0; c < 4; ++c)
                Ush[(ty << 2) + a][(tx << 2) + c] =
                    V[r0 + (ty << 2) + a][(tx << 2) + c] - acc[a][c];
        __syncthreads();
        // V_k = W_k @ U : stage WinvT rows (contiguous) as A-operand
        float acc2[4][4] = {};
        const float* WTk = WbT + (size_t)k * 64 * 64;
        for (int k0 = 0; k0 < 64; k0 += BK) {
            *(float4*)&Wt[wk][wq] = *(const float4*)(WTk + (size_t)(k0 + wk) * 64 + wq);
            __syncthreads();
            {
                float (*acc)[4] = acc2;             // reuse MICRO on acc2
                MICRO(Wt, (Ush + k0));
            }
            __syncthreads();
        }
#pragma unroll
        for (int a = 0; a < 4; ++a)
#pragma unroll
            for (int c = 0; c < 4; ++c)
                V[r0 + (ty << 2) + a][(tx << 2) + c] = acc2[a][c];
        __syncthreads();
    }

    // ---- backward: Z_k = W_k^T (V_k - L[64(k+1):, k]^T @ Z) ----
    for (int k = 7; k >= 0; --k) {
        const int r0 = k * 64;
        float acc[4][4] = {};
        for (int m0 = r0 + 64; m0 < 512; m0 += BK) {  // K over rows below
            // St[kk][r] = A[(m0+kk)*512 + r0 + r]  (row-contiguous read!)
            *(float4*)&St[wk][wq] = *(const float4*)(A + (size_t)(m0 + wk) * 512 + r0 + wq);
            __syncthreads();
            MICRO(St, (V + m0));
            __syncthreads();
        }
#pragma unroll
        for (int a = 0; a < 4; ++a)
#pragma unroll
            for (int c = 0; c < 4; ++c)
                Ush[(ty << 2) + a][(tx << 2) + c] =
                    V[r0 + (ty << 2) + a][(tx << 2) + c] - acc[a][c];
        __syncthreads();
        // Z_k = W_k^T @ U : A-op[r][m] = W[m][r] -> stage Winv rows (contiguous)
        float acc2[4][4] = {};
        const float* Wk = Wb + (size_t)k * 64 * 64;
        for (int k0 = 0; k0 < 64; k0 += BK) {
            *(float4*)&Wt[wk][wq] = *(const float4*)(Wk + (size_t)(k0 + wk) * 64 + wq);
            __syncthreads();
            {
                float (*acc)[4] = acc2;
                MICRO(Wt, (Ush + k0));
            }
            __syncthreads();
        }
#pragma unroll
        for (int a = 0; a < 4; ++a)
#pragma unroll
            for (int c = 0; c < 4; ++c)
                V[r0 + (ty << 2) + a][(tx << 2) + c] = acc2[a][c];
        __syncthreads();
    }

    for (int t = tid; t < 512 * 16; t += 256) {
        const int row = t >> 4, c4 = (t & 15) << 2;
        *(float4*)(Z + (size_t)row * 64 + c4) = *(const float4*)&V[row][c4];
    }
}

// w[b] (2048x64) = RS_b^T @ Z_b   (K = 512)
__global__ __launch_bounds__(256)
void out_kernel(const float* __restrict__ RS, const float* __restrict__ Z,
                float* __restrict__ Wout)
{
    __shared__ float Rt[BK][64 + 4];
    __shared__ float Zt[BK][64 + 4];
    const int tid = threadIdx.x;
    const int b   = blockIdx.y;
    const int d0  = blockIdx.x * 64;
    const int kk  = tid >> 4, cq = (tid & 15) << 2;
    const int ty  = tid >> 4, tx = tid & 15;
    float acc[4][4] = {};

    for (int k0 = 0; k0 < Tt; k0 += BK) {
        *(float4*)&Rt[kk][cq] =
            *(const float4*)(RS + ((size_t)b * Tt + k0 + kk) * RES + d0 + cq);
        *(float4*)&Zt[kk][cq] =
            *(const float4*)(Z + ((size_t)b * Tt + k0 + kk) * OUTd + cq);
        __syncthreads();
        MICRO(Rt, Zt);
        __syncthreads();
    }
#pragma unroll
    for (int a = 0; a < 4; ++a) {
        const int d = d0 + (ty << 2) + a;
        float4 v = make_float4(acc[a][0], acc[a][1], acc[a][2], acc[a][3]);
        *(float4*)(Wout + ((size_t)b * RES + d) * OUTd + (tx << 2)) = v;
    }
}

// bias[b][o] = sum_n Z[b][n][o]
__global__ __launch_bounds__(64)
void bias_kernel(const float* __restrict__ Z, float* __restrict__ Bout)
{
    const int b = blockIdx.x, o = threadIdx.x;
    const float* Zb = Z + (size_t)b * Tt * OUTd;
    float s = 0.f;
    for (int n = 0; n < Tt; ++n) s += Zb[(size_t)n * OUTd + o];
    Bout[(size_t)b * OUTd + o] = s;
}

extern "C" void kernel_launch(void* const* d_in, const int* in_sizes, int n_in,
                              void* d_out, int out_size, void* d_ws, size_t ws_size,
                              hipStream_t stream)
{
    const float* X    = (const float*)d_in[0];   // (32,512,128)
    const float* Y    = (const float*)d_in[1];   // (32,512,64)
    const float* Wres = (const float*)d_in[2];   // (2048,2048)
    const float* Win  = (const float*)d_in[3];   // (128,2048)
    const float* lam  = (const float*)d_in[4];   // scalar

    float* out  = (float*)d_out;
    float* Wout = out;                            // 32*2048*64
    float* Bout = out + (size_t)Bb * RES * OUTd;  // 32*64

    // workspace (floats): S0 | S1 | RS = 8.4M | 8.4M | 33.6M = 192 MB.
    // A (8.4M) overlays S0. Z(1M)+Winv(1M)+WinvT(1M) overlay S1.
    float* ws   = (float*)d_ws;
    float* S0   = ws;
    float* S1   = S0 + (size_t)NROW * RES;
    float* RSb  = S1 + (size_t)NROW * RES;
    float* A    = S0;
    float* Z    = S1;
    float* Wi   = S1 + (size_t)Bb * Tt * OUTd;          // 1,048,576 floats
    float* WiT  = Wi + (size_t)Bb * 8 * 64 * 64;        // 1,048,576 floats

    const dim3 sgrid(RES / BN, NROW / BM);   // (32, 64)
    const dim3 blk(256);
    step_kernel<<<sgrid, blk, 0, stream>>>(nullptr, X, Wres, Win, S0, 0);
    step_kernel<<<sgrid, blk, 0, stream>>>(S0, X, Wres, Win, S1, 1);
    step_kernel<<<sgrid, blk, 0, stream>>>(S1, X, Wres, Win, RSb, 2);
    step_kernel<<<sgrid, blk, 0, stream>>>(RSb, X, Wres, Win, RSb, 3);
    step_kernel<<<sgrid, blk, 0, stream>>>(RSb, X, Wres, Win, RSb, 4);
    step_kernel<<<sgrid, blk, 0, stream>>>(RSb, X, Wres, Win, RSb, 5);

    gram_kernel<<<dim3(36, Bb), blk, 0, stream>>>(RSb, A, lam);

    for (int k = 0; k < 8; ++k) {
        chol_panel_kernel<<<dim3(Bb), dim3(512), 0, stream>>>(A, k);
        const int m = 7 - k;
        if (m > 0) {
            const int tiles = m * (m + 1) / 2;
            chol_trailing_kernel<<<dim3(tiles, Bb), blk, 0, stream>>>(A, k);
        }
    }
    tri_inv_kernel<<<dim3(Bb * 8), dim3(64), 0, stream>>>(A, Wi, WiT);
    fb_solve2_kernel<<<dim3(Bb), dim3(256), 0, stream>>>(A, Wi, WiT, Y, Z);

    out_kernel<<<dim3(RES / 64, Bb), blk, 0, stream>>>(RSb, Z, Wout);
    bias_kernel<<<dim3(Bb), dim3(OUTd), 0, stream>>>(Z, Bout);
}

// Round 5
// 4445.310 us; speedup vs baseline: 3.4579x; 1.2518x over previous
//
#include <hip/hip_runtime.h>
#include <cmath>

// Problem constants
#define Bb   32
#define Tt   512
#define INd  128
#define RES  2048
#define OUTd 64
#define NWIN 128

// fp32 GEMM tiling (chol/out/solve kernels)
#define BM 64
#define BN 64
#define BK 16

typedef unsigned short u16;
typedef __attribute__((ext_vector_type(8))) short bf8;            // 8 bf16 = 4 VGPRs
typedef __attribute__((ext_vector_type(8))) unsigned short u16x8;
typedef __attribute__((ext_vector_type(4))) float f32x4;

// Split fp32 into bf16 hi (RNE) + lo (trunc of exact residual). a ~= hi+lo with
// |err| <= 2^-17|a|; dropped lo*lo term in products <= 2^-16 -> ~fp32 GEMM.
__device__ __forceinline__ void splitf(float a, u16& h, u16& l) {
    unsigned u = __float_as_uint(a);
    unsigned r = (u + 0x7fffu + ((u >> 16) & 1u)) & 0xffff0000u;   // RNE to bf16
    h = (u16)(r >> 16);
    float d = a - __uint_as_float(r);                              // exact
    l = (u16)(__float_as_uint(d) >> 16);
}

#define MICRO(SA, SB)                                                           \
  do {                                                                          \
    _Pragma("unroll")                                                           \
    for (int kk = 0; kk < BK; ++kk) {                                           \
      const float4 a4 = *(const float4*)&SA[kk][ty << 2];                       \
      const float4 b4 = *(const float4*)&SB[kk][tx << 2];                       \
      acc[0][0] += a4.x*b4.x; acc[0][1] += a4.x*b4.y;                           \
      acc[0][2] += a4.x*b4.z; acc[0][3] += a4.x*b4.w;                           \
      acc[1][0] += a4.y*b4.x; acc[1][1] += a4.y*b4.y;                           \
      acc[1][2] += a4.y*b4.z; acc[1][3] += a4.y*b4.w;                           \
      acc[2][0] += a4.z*b4.x; acc[2][1] += a4.z*b4.y;                           \
      acc[2][2] += a4.z*b4.z; acc[2][3] += a4.z*b4.w;                           \
      acc[3][0] += a4.w*b4.x; acc[3][1] += a4.w*b4.y;                           \
      acc[3][2] += a4.w*b4.z; acc[3][3] += a4.w*b4.w;                           \
    }                                                                           \
  } while (0)

// bf16x3 MFMA over staged 128x128 tile slice (K=32). Each of 4 waves does a
// 64x64 sub-tile as 4x4 frags of 16x16x32, 3 products each.
#define MFMA_TILE()                                                              \
  do {                                                                           \
    bf8 aH[4], aL[4], bH[4], bL[4];                                              \
    _Pragma("unroll")                                                            \
    for (int i = 0; i < 4; ++i) {                                                \
      const int ar = (wm*64 + i*16 + l15)*40 + quad*8;                           \
      aH[i] = *(const bf8*)&Ah[ar]; aL[i] = *(const bf8*)&Al[ar];                \
      const int br = (wn*64 + i*16 + l15)*40 + quad*8;                           \
      bH[i] = *(const bf8*)&Bh[br]; bL[i] = *(const bf8*)&Bl[br];                \
    }                                                                            \
    _Pragma("unroll")                                                            \
    for (int i = 0; i < 4; ++i)                                                  \
      _Pragma("unroll")                                                          \
      for (int j = 0; j < 4; ++j) {                                              \
        acc[i][j] = __builtin_amdgcn_mfma_f32_16x16x32_bf16(aH[i], bH[j], acc[i][j], 0, 0, 0); \
        acc[i][j] = __builtin_amdgcn_mfma_f32_16x16x32_bf16(aH[i], bL[j], acc[i][j], 0, 0, 0); \
        acc[i][j] = __builtin_amdgcn_mfma_f32_16x16x32_bf16(aL[i], bH[j], acc[i][j], 0, 0, 0); \
      }                                                                          \
  } while (0)

// Transpose + split: in (K x N fp32, row-major) -> outH/outL (N x K bf16).
__global__ __launch_bounds__(256)
void tconv_kernel(const float* __restrict__ in, u16* __restrict__ outH,
                  u16* __restrict__ outL, int K, int N)
{
    __shared__ float T[64][65];
    const int n0 = blockIdx.x * 64, k0 = blockIdx.y * 64;
    const int t = threadIdx.x;
    const int r = t >> 2, c0 = (t & 3) * 16;
#pragma unroll
    for (int i = 0; i < 4; ++i) {
        const float4 v = *(const float4*)&in[(size_t)(k0 + r) * N + n0 + c0 + 4*i];
        T[r][c0 + 4*i + 0] = v.x; T[r][c0 + 4*i + 1] = v.y;
        T[r][c0 + 4*i + 2] = v.z; T[r][c0 + 4*i + 3] = v.w;
    }
    __syncthreads();
    const int n = t >> 2, ck = (t & 3) * 16;
    u16x8 h0, h1, l0, l1;
#pragma unroll
    for (int i = 0; i < 8; ++i) { u16 h, l; splitf(T[ck + i][n], h, l); h0[i] = h; l0[i] = l; }
#pragma unroll
    for (int i = 0; i < 8; ++i) { u16 h, l; splitf(T[ck + 8 + i][n], h, l); h1[i] = h; l1[i] = l; }
    const size_t ob = (size_t)(n0 + n) * K + k0 + ck;
    *(u16x8*)&outH[ob] = h0; *(u16x8*)&outH[ob + 8] = h1;
    *(u16x8*)&outL[ob] = l0; *(u16x8*)&outL[ob + 8] = l1;
}

// One reservoir step via bf16x3 MFMA.
// State rows live inside RS at row b*512 + 4w + class; cin/cout select class.
// s==0: no state GEMM, prev=0.
__global__ __launch_bounds__(256)
void step_mfma_kernel(float* __restrict__ Sio, const float* __restrict__ X,
                      const u16* __restrict__ WTh, const u16* __restrict__ WTl,
                      const u16* __restrict__ WinTh, const u16* __restrict__ WinTl,
                      int cin, int cout, int s)
{
    __shared__ u16 Ah[128 * 40], Al[128 * 40], Bh[128 * 40], Bl[128 * 40];
    const int tid = threadIdx.x;
    const int q0  = blockIdx.x * 128;         // reservoir-col tile
    const int b   = blockIdx.y;               // batch (128 w-rows per block)
    const int bofs = b * Tt;
    const int wid = tid >> 6, lane = tid & 63;
    const int wm = wid & 1, wn = wid >> 1;
    const int l15 = lane & 15, quad = lane >> 4;

    f32x4 acc[4][4];
    const f32x4 zz = {0.f, 0.f, 0.f, 0.f};
#pragma unroll
    for (int i = 0; i < 4; ++i)
#pragma unroll
        for (int j = 0; j < 4; ++j) acc[i][j] = zz;

    if (s > 0) {
        float4 pa[2][2]; u16x8 pbh[2], pbl[2];
#define LOAD_STATE(K0)                                                          \
        _Pragma("unroll")                                                       \
        for (int cc = 0; cc < 2; ++cc) {                                        \
            const int c = tid + cc * 256, row = c >> 2, seg = c & 3;            \
            const size_t ar = (size_t)(bofs + 4*row + cin) * RES + (K0) + seg*8;\
            pa[cc][0] = *(const float4*)&Sio[ar];                               \
            pa[cc][1] = *(const float4*)&Sio[ar + 4];                           \
            const size_t br = (size_t)(q0 + row) * RES + (K0) + seg*8;          \
            pbh[cc] = *(const u16x8*)&WTh[br];                                  \
            pbl[cc] = *(const u16x8*)&WTl[br];                                  \
        }
        LOAD_STATE(0)
        for (int k0 = 0; k0 < RES; k0 += 32) {
            if (k0) __syncthreads();
#pragma unroll
            for (int cc = 0; cc < 2; ++cc) {
                const int c = tid + cc * 256, row = c >> 2, seg = c & 3;
                float vs[8] = {pa[cc][0].x, pa[cc][0].y, pa[cc][0].z, pa[cc][0].w,
                               pa[cc][1].x, pa[cc][1].y, pa[cc][1].z, pa[cc][1].w};
                u16x8 h, l;
#pragma unroll
                for (int e = 0; e < 8; ++e) { u16 hh, ll; splitf(vs[e], hh, ll); h[e] = hh; l[e] = ll; }
                const int li = row * 40 + seg * 8;
                *(u16x8*)&Ah[li] = h; *(u16x8*)&Al[li] = l;
                *(u16x8*)&Bh[li] = pbh[cc]; *(u16x8*)&Bl[li] = pbl[cc];
            }
            __syncthreads();
            if (k0 + 32 < RES) { LOAD_STATE(k0 + 32) }
            MFMA_TILE();
        }
        __syncthreads();
#undef LOAD_STATE
    }

    // input projection: K = 128 over x[b, 4w+s-2, :] @ Win
    for (int k0 = 0; k0 < INd; k0 += 32) {
#pragma unroll
        for (int cc = 0; cc < 2; ++cc) {
            const int c = tid + cc * 256, row = c >> 2, seg = c & 3;
            const int t = 4 * row + s - 2;
            u16x8 h, l;
#pragma unroll
            for (int e = 0; e < 8; ++e) { h[e] = 0; l[e] = 0; }
            if (t >= 0) {
                const size_t xr = ((size_t)(bofs + t)) * INd + k0 + seg * 8;
                const float4 v0 = *(const float4*)&X[xr];
                const float4 v1 = *(const float4*)&X[xr + 4];
                float vs[8] = {v0.x, v0.y, v0.z, v0.w, v1.x, v1.y, v1.z, v1.w};
#pragma unroll
                for (int e = 0; e < 8; ++e) { u16 hh, ll; splitf(vs[e], hh, ll); h[e] = hh; l[e] = ll; }
            }
            const int li = row * 40 + seg * 8;
            *(u16x8*)&Ah[li] = h; *(u16x8*)&Al[li] = l;
            const size_t br = (size_t)(q0 + row) * INd + k0 + seg * 8;
            *(u16x8*)&Bh[li] = *(const u16x8*)&WinTh[br];
            *(u16x8*)&Bl[li] = *(const u16x8*)&WinTl[br];
        }
        __syncthreads();
        MFMA_TILE();
        __syncthreads();
    }

    // epilogue: v = 0.7*prev + 0.3*sin(acc); write class cout
#pragma unroll
    for (int i = 0; i < 4; ++i)
#pragma unroll
        for (int j = 0; j < 4; ++j)
#pragma unroll
            for (int rg = 0; rg < 4; ++rg) {
                const int rr = wm * 64 + i * 16 + quad * 4 + rg;   // w index
                const int q  = q0 + wn * 64 + j * 16 + l15;
                float v = acc[i][j][rg];
                float prev = 0.f;
                if (s > 0) prev = Sio[(size_t)(bofs + 4*rr + cin) * RES + q];
                v = 0.7f * prev + 0.3f * sinf(v);
                Sio[(size_t)(bofs + 4*rr + cout) * RES + q] = v;
            }
}

// Gram via bf16x3 MFMA: A[b] = RS_b RS_b^T + ones + reg*I (lower tile pairs).
__global__ __launch_bounds__(256)
void gram_mfma_kernel(const float* __restrict__ RS, float* __restrict__ A,
                      const float* __restrict__ lam)
{
    __shared__ u16 Ah[128 * 40], Al[128 * 40], Bh[128 * 40], Bl[128 * 40];
    const int tid = threadIdx.x;
    const int bt  = blockIdx.y;
    int ti = 0, rem = (int)blockIdx.x;
    while (rem >= 4 - ti) { rem -= 4 - ti; ++ti; }
    const int tj = ti + rem;
    const int n0 = ti * 128, m0 = tj * 128;
    const float* base = RS + (size_t)bt * Tt * RES;

    const int wid = tid >> 6, lane = tid & 63;
    const int wm = wid & 1, wn = wid >> 1;
    const int l15 = lane & 15, quad = lane >> 4;

    f32x4 acc[4][4];
    const f32x4 zz = {0.f, 0.f, 0.f, 0.f};
#pragma unroll
    for (int i = 0; i < 4; ++i)
#pragma unroll
        for (int j = 0; j < 4; ++j) acc[i][j] = zz;

    float4 pa[2][2], pb[2][2];
#define LOAD_G(K0)                                                              \
    _Pragma("unroll")                                                           \
    for (int cc = 0; cc < 2; ++cc) {                                            \
        const int c = tid + cc * 256, row = c >> 2, seg = c & 3;                \
        const size_t ar = (size_t)(n0 + row) * RES + (K0) + seg * 8;            \
        pa[cc][0] = *(const float4*)&base[ar];                                  \
        pa[cc][1] = *(const float4*)&base[ar + 4];                              \
        const size_t br = (size_t)(m0 + row) * RES + (K0) + seg * 8;            \
        pb[cc][0] = *(const float4*)&base[br];                                  \
        pb[cc][1] = *(const float4*)&base[br + 4];                              \
    }
    LOAD_G(0)
    for (int k0 = 0; k0 < RES; k0 += 32) {
        if (k0) __syncthreads();
#pragma unroll
        for (int cc = 0; cc < 2; ++cc) {
            const int c = tid + cc * 256, row = c >> 2, seg = c & 3;
            float va[8] = {pa[cc][0].x, pa[cc][0].y, pa[cc][0].z, pa[cc][0].w,
                           pa[cc][1].x, pa[cc][1].y, pa[cc][1].z, pa[cc][1].w};
            float vb[8] = {pb[cc][0].x, pb[cc][0].y, pb[cc][0].z, pb[cc][0].w,
                           pb[cc][1].x, pb[cc][1].y, pb[cc][1].z, pb[cc][1].w};
            u16x8 ha, la, hb, lb;
#pragma unroll
            for (int e = 0; e < 8; ++e) {
                u16 hh, ll;
                splitf(va[e], hh, ll); ha[e] = hh; la[e] = ll;
                splitf(vb[e], hh, ll); hb[e] = hh; lb[e] = ll;
            }
            const int li = row * 40 + seg * 8;
            *(u16x8*)&Ah[li] = ha; *(u16x8*)&Al[li] = la;
            *(u16x8*)&Bh[li] = hb; *(u16x8*)&Bl[li] = lb;
        }
        __syncthreads();
        if (k0 + 32 < RES) { LOAD_G(k0 + 32) }
        MFMA_TILE();
    }
#undef LOAD_G
    const float reg = log1pf(expf(lam[0]));
    float* Ab = A + (size_t)bt * 512 * 512;
#pragma unroll
    for (int i = 0; i < 4; ++i)
#pragma unroll
        for (int j = 0; j < 4; ++j)
#pragma unroll
            for (int rg = 0; rg < 4; ++rg) {
                const int nn = n0 + wm * 64 + i * 16 + quad * 4 + rg;
                const int mm = m0 + wn * 64 + j * 16 + l15;
                float val = acc[i][j][rg] + 1.0f;
                if (nn == mm) val += reg;
                Ab[(size_t)nn * 512 + mm] = val;
                Ab[(size_t)mm * 512 + nn] = val;
            }
}

// ---- Blocked Cholesky (unchanged from R4) ----
__global__ __launch_bounds__(512)
void chol_panel_kernel(float* __restrict__ Aall, int k)
{
    __shared__ float P[512][65];
    __shared__ float dsh;
    float* A = Aall + (size_t)blockIdx.x * 512 * 512;
    const int tid  = threadIdx.x;
    const int j0   = 64 * k;
    const int rows = 512 - j0;
    const int c4   = (tid & 15) << 2;

    for (int r = tid >> 4; r < rows; r += 32) {
        const float4 v = *(const float4*)(A + (size_t)(j0 + r) * 512 + j0 + c4);
        P[r][c4 + 0] = v.x; P[r][c4 + 1] = v.y;
        P[r][c4 + 2] = v.z; P[r][c4 + 3] = v.w;
    }
    __syncthreads();

    const int lane = tid & 63, wv = tid >> 6;
    for (int j = 0; j < 64; ++j) {
        if (tid == 0) dsh = sqrtf(P[j][j]);
        __syncthreads();
        const float rd = 1.0f / dsh;
        for (int i = j + 1 + tid; i < rows; i += 512)
            P[i][j] *= rd;
        if (tid == 0) P[j][j] = dsh;
        __syncthreads();
        const int c = j + 1 + lane;
        for (int i = j + 1 + wv; i < rows; i += 8) {
            const float lij = P[i][j];
            if (c < 64 && c <= i)
                P[i][c] -= lij * P[c][j];
        }
        __syncthreads();
    }

    for (int r = tid >> 4; r < rows; r += 32) {
        const float4 v = make_float4(P[r][c4], P[r][c4 + 1],
                                     P[r][c4 + 2], P[r][c4 + 3]);
        *(float4*)(A + (size_t)(j0 + r) * 512 + j0 + c4) = v;
    }
}

__global__ __launch_bounds__(256)
void chol_trailing_kernel(float* __restrict__ Aall, int k)
{
    __shared__ float Ut[BK][BM + 4];
    __shared__ float Vt[BK][BN + 4];
    float* A = Aall + (size_t)blockIdx.y * 512 * 512;
    const int tid = threadIdx.x;
    int a = 0, rem = (int)blockIdx.x;
    while (rem >= a + 1) { rem -= a + 1; ++a; }
    const int ti = k + 1 + a, tj = k + 1 + rem;
    const int i0 = ti * 64, j0c = tj * 64, p0 = k * 64;

    const int li = tid >> 2, lk = (tid & 3) << 2;
    const int ty = tid >> 4, tx = tid & 15;
    float acc[4][4] = {};

    for (int k0 = 0; k0 < 64; k0 += BK) {
        const float4 u = *(const float4*)(A + (size_t)(i0 + li) * 512 + p0 + k0 + lk);
        const float4 v = *(const float4*)(A + (size_t)(j0c + li) * 512 + p0 + k0 + lk);
        Ut[lk + 0][li] = u.x; Ut[lk + 1][li] = u.y;
        Ut[lk + 2][li] = u.z; Ut[lk + 3][li] = u.w;
        Vt[lk + 0][li] = v.x; Vt[lk + 1][li] = v.y;
        Vt[lk + 2][li] = v.z; Vt[lk + 3][li] = v.w;
        __syncthreads();
        MICRO(Ut, Vt);
        __syncthreads();
    }
#pragma unroll
    for (int aa = 0; aa < 4; ++aa) {
        const int r = i0 + (ty << 2) + aa;
        float* crow = A + (size_t)r * 512 + j0c + (tx << 2);
        float4 cv = *(const float4*)crow;
        cv.x -= acc[aa][0]; cv.y -= acc[aa][1];
        cv.z -= acc[aa][2]; cv.w -= acc[aa][3];
        *(float4*)crow = cv;
    }
}

__global__ __launch_bounds__(64)
void tri_inv_kernel(const float* __restrict__ Aall, float* __restrict__ Winv,
                    float* __restrict__ WinvT)
{
    __shared__ float L[64][65];
    __shared__ float W[64][65];
    const int b = blockIdx.x >> 3, k = blockIdx.x & 7;
    const int c = threadIdx.x;
    const float* Ab = Aall + (size_t)b * 512 * 512;
    const int j0 = k * 64;

    for (int j = 0; j < 64; ++j) {
        L[j][c] = Ab[(size_t)(j0 + j) * 512 + j0 + c];
        W[j][c] = 0.f;
    }
    __syncthreads();
    for (int j = 0; j < 64; ++j) {
        float s = (j == c) ? 1.0f : 0.0f;
        for (int m = 0; m < j; ++m)
            s -= L[j][m] * W[m][c];
        W[j][c] = (c <= j) ? (s / L[j][j]) : 0.0f;
        __syncthreads();
    }
    float* Wo  = Winv  + ((size_t)b * 8 + k) * 64 * 64;
    float* WoT = WinvT + ((size_t)b * 8 + k) * 64 * 64;
    for (int j = 0; j < 64; ++j) {
        Wo[(size_t)j * 64 + c]  = W[j][c];
        WoT[(size_t)c * 64 + j] = W[j][c];
    }
}

__global__ __launch_bounds__(256)
void fb_solve2_kernel(const float* __restrict__ Aall,
                      const float* __restrict__ Winv,
                      const float* __restrict__ WinvT,
                      const float* __restrict__ Y, float* __restrict__ Zall)
{
    __shared__ float V[512][64];
    __shared__ float St[BK][68];
    __shared__ float Wt[BK][68];
    __shared__ float Ush[64][68];
    const int b   = blockIdx.x, tid = threadIdx.x;
    const float* A   = Aall + (size_t)b * 512 * 512;
    const float* Yb  = Y    + (size_t)b * 512 * OUTd;
    float* Z         = Zall + (size_t)b * 512 * OUTd;
    const float* Wb  = Winv  + (size_t)b * 8 * 64 * 64;
    const float* WbT = WinvT + (size_t)b * 8 * 64 * 64;

    const int li = tid >> 2, lk = (tid & 3) << 2;
    const int wk = tid >> 4, wq = (tid & 15) << 2;
    const int ty = tid >> 4, tx = tid & 15;

    for (int t = tid; t < 512 * 16; t += 256) {
        const int row = t >> 4, c4 = (t & 15) << 2;
        *(float4*)&V[row][c4] = *(const float4*)(Yb + (size_t)row * 64 + c4);
    }
    __syncthreads();

    for (int k = 0; k < 8; ++k) {
        const int r0 = k * 64;
        float acc[4][4] = {};
        for (int k0 = 0; k0 < r0; k0 += BK) {
            const float4 u = *(const float4*)(A + (size_t)(r0 + li) * 512 + k0 + lk);
            St[lk + 0][li] = u.x; St[lk + 1][li] = u.y;
            St[lk + 2][li] = u.z; St[lk + 3][li] = u.w;
            __syncthreads();
            MICRO(St, (V + k0));
            __syncthreads();
        }
#pragma unroll
        for (int a = 0; a < 4; ++a)
#pragma unroll
            for (int c = 0; c < 4; ++c)
                Ush[(ty << 2) + a][(tx << 2) + c] =
                    V[r0 + (ty << 2) + a][(tx << 2) + c] - acc[a][c];
        __syncthreads();
        float acc2[4][4] = {};
        const float* WTk = WbT + (size_t)k * 64 * 64;
        for (int k0 = 0; k0 < 64; k0 += BK) {
            *(float4*)&Wt[wk][wq] = *(const float4*)(WTk + (size_t)(k0 + wk) * 64 + wq);
            __syncthreads();
            {
                float (*acc)[4] = acc2;
                MICRO(Wt, (Ush + k0));
            }
            __syncthreads();
        }
#pragma unroll
        for (int a = 0; a < 4; ++a)
#pragma unroll
            for (int c = 0; c < 4; ++c)
                V[r0 + (ty << 2) + a][(tx << 2) + c] = acc2[a][c];
        __syncthreads();
    }

    for (int k = 7; k >= 0; --k) {
        const int r0 = k * 64;
        float acc[4][4] = {};
        for (int m0 = r0 + 64; m0 < 512; m0 += BK) {
            *(float4*)&St[wk][wq] = *(const float4*)(A + (size_t)(m0 + wk) * 512 + r0 + wq);
            __syncthreads();
            MICRO(St, (V + m0));
            __syncthreads();
        }
#pragma unroll
        for (int a = 0; a < 4; ++a)
#pragma unroll
            for (int c = 0; c < 4; ++c)
                Ush[(ty << 2) + a][(tx << 2) + c] =
                    V[r0 + (ty << 2) + a][(tx << 2) + c] - acc[a][c];
        __syncthreads();
        float acc2[4][4] = {};
        const float* Wk = Wb + (size_t)k * 64 * 64;
        for (int k0 = 0; k0 < 64; k0 += BK) {
            *(float4*)&Wt[wk][wq] = *(const float4*)(Wk + (size_t)(k0 + wk) * 64 + wq);
            __syncthreads();
            {
                float (*acc)[4] = acc2;
                MICRO(Wt, (Ush + k0));
            }
            __syncthreads();
        }
#pragma unroll
        for (int a = 0; a < 4; ++a)
#pragma unroll
            for (int c = 0; c < 4; ++c)
                V[r0 + (ty << 2) + a][(tx << 2) + c] = acc2[a][c];
        __syncthreads();
    }

    for (int t = tid; t < 512 * 16; t += 256) {
        const int row = t >> 4, c4 = (t & 15) << 2;
        *(float4*)(Z + (size_t)row * 64 + c4) = *(const float4*)&V[row][c4];
    }
}

// w[b] (2048x64) = RS_b^T @ Z_b   (K = 512)
__global__ __launch_bounds__(256)
void out_kernel(const float* __restrict__ RS, const float* __restrict__ Z,
                float* __restrict__ Wout)
{
    __shared__ float Rt[BK][64 + 4];
    __shared__ float Zt[BK][64 + 4];
    const int tid = threadIdx.x;
    const int b   = blockIdx.y;
    const int d0  = blockIdx.x * 64;
    const int kk  = tid >> 4, cq = (tid & 15) << 2;
    const int ty  = tid >> 4, tx = tid & 15;
    float acc[4][4] = {};

    for (int k0 = 0; k0 < Tt; k0 += BK) {
        *(float4*)&Rt[kk][cq] =
            *(const float4*)(RS + ((size_t)b * Tt + k0 + kk) * RES + d0 + cq);
        *(float4*)&Zt[kk][cq] =
            *(const float4*)(Z + ((size_t)b * Tt + k0 + kk) * OUTd + cq);
        __syncthreads();
        MICRO(Rt, Zt);
        __syncthreads();
    }
#pragma unroll
    for (int a = 0; a < 4; ++a) {
        const int d = d0 + (ty << 2) + a;
        float4 v = make_float4(acc[a][0], acc[a][1], acc[a][2], acc[a][3]);
        *(float4*)(Wout + ((size_t)b * RES + d) * OUTd + (tx << 2)) = v;
    }
}

__global__ __launch_bounds__(64)
void bias_kernel(const float* __restrict__ Z, float* __restrict__ Bout)
{
    const int b = blockIdx.x, o = threadIdx.x;
    const float* Zb = Z + (size_t)b * Tt * OUTd;
    float s = 0.f;
    for (int n = 0; n < Tt; ++n) s += Zb[(size_t)n * OUTd + o];
    Bout[(size_t)b * OUTd + o] = s;
}

extern "C" void kernel_launch(void* const* d_in, const int* in_sizes, int n_in,
                              void* d_out, int out_size, void* d_ws, size_t ws_size,
                              hipStream_t stream)
{
    const float* X    = (const float*)d_in[0];   // (32,512,128)
    const float* Y    = (const float*)d_in[1];   // (32,512,64)
    const float* Wres = (const float*)d_in[2];   // (2048,2048)
    const float* Win  = (const float*)d_in[3];   // (128,2048)
    const float* lam  = (const float*)d_in[4];   // scalar

    float* out  = (float*)d_out;
    float* Wout = out;
    float* Bout = out + (size_t)Bb * RES * OUTd;

    // workspace: RS(128MB) | WTh/WTl(16MB) | WinTh/WinTl(1MB) | A(32) Z(4) Wi(4) WiT(4) = 189MB
    char* p = (char*)d_ws;
    float* RS = (float*)p;            p += (size_t)Bb * Tt * RES * 4;   // 128 MB
    u16* WTh   = (u16*)p;             p += (size_t)RES * RES * 2;       // 8 MB
    u16* WTl   = (u16*)p;             p += (size_t)RES * RES * 2;
    u16* WinTh = (u16*)p;             p += (size_t)INd * RES * 2;       // 0.5 MB
    u16* WinTl = (u16*)p;             p += (size_t)INd * RES * 2;
    float* A   = (float*)p;           p += (size_t)Bb * 512 * 512 * 4;  // 32 MB
    float* Z   = (float*)p;           p += (size_t)Bb * Tt * OUTd * 4;  // 4 MB
    float* Wi  = (float*)p;           p += (size_t)Bb * 8 * 64 * 64 * 4;
    float* WiT = (float*)p;

    const dim3 blk(256);
    tconv_kernel<<<dim3(RES / 64, RES / 64), blk, 0, stream>>>(Wres, WTh, WTl, RES, RES);
    tconv_kernel<<<dim3(RES / 64, INd / 64), blk, 0, stream>>>(Win, WinTh, WinTl, INd, RES);

    // state classes in RS rows b*512+4w+c: s:(cin->cout) 0:(-,2) 1:(2,1) 2:(1,0) 3:(0,1) 4:(1,2) 5:(2,3)
    const dim3 sgrid(RES / 128, Bb);
    step_mfma_kernel<<<sgrid, blk, 0, stream>>>(RS, X, WTh, WTl, WinTh, WinTl, 0, 2, 0);
    step_mfma_kernel<<<sgrid, blk, 0, stream>>>(RS, X, WTh, WTl, WinTh, WinTl, 2, 1, 1);
    step_mfma_kernel<<<sgrid, blk, 0, stream>>>(RS, X, WTh, WTl, WinTh, WinTl, 1, 0, 2);
    step_mfma_kernel<<<sgrid, blk, 0, stream>>>(RS, X, WTh, WTl, WinTh, WinTl, 0, 1, 3);
    step_mfma_kernel<<<sgrid, blk, 0, stream>>>(RS, X, WTh, WTl, WinTh, WinTl, 1, 2, 4);
    step_mfma_kernel<<<sgrid, blk, 0, stream>>>(RS, X, WTh, WTl, WinTh, WinTl, 2, 3, 5);

    gram_mfma_kernel<<<dim3(10, Bb), blk, 0, stream>>>(RS, A, lam);

    for (int k = 0; k < 8; ++k) {
        chol_panel_kernel<<<dim3(Bb), dim3(512), 0, stream>>>(A, k);
        const int m = 7 - k;
        if (m > 0) {
            const int tiles = m * (m + 1) / 2;
            chol_trailing_kernel<<<dim3(tiles, Bb), blk, 0, stream>>>(A, k);
        }
    }
    tri_inv_kernel<<<dim3(Bb * 8), dim3(64), 0, stream>>>(A, Wi, WiT);
    fb_solve2_kernel<<<dim3(Bb), blk, 0, stream>>>(A, Wi, WiT, Y, Z);

    out_kernel<<<dim3(RES / 64, Bb), blk, 0, stream>>>(RS, Z, Wout);
    bias_kernel<<<dim3(Bb), dim3(OUTd), 0, stream>>>(Z, Bout);
}